// Round 6
// baseline (542.717 us; speedup 1.0000x reference)
//
#include <hip/hip_runtime.h>
#include <hip/hip_cooperative_groups.h>

namespace cg = cooperative_groups;

#define BB 2
#define SS 2048
#define DD 1024
#define HH 16
#define HD 64
#define MM (BB*SS)   // 4096
#define KC 2                 // flash split-K chunks
#define KT_PER (SS/64/KC)    // 16 tiles per chunk

#define NB_CONV 2048
#define NB_TRAN 2048
#define NB_PREC 4100
#define NB_ZERO 64
#define NB_PREP (NB_CONV+NB_TRAN+NB_PREC+NB_ZERO)
#define NB_GEMM 1024
#define NB_FLASH (32*HH*BB*KC)   // 2048

typedef unsigned short u16;
typedef __attribute__((ext_vector_type(8))) short bf16x8;
typedef __attribute__((ext_vector_type(4))) float f32x4;

typedef __attribute__((address_space(1))) const unsigned int* gas_t;
typedef __attribute__((address_space(3))) unsigned int* las_t;

#ifndef __has_builtin
#define __has_builtin(x) 0
#endif
#if __has_builtin(__builtin_amdgcn_exp2f)
#define EXP2F(x) __builtin_amdgcn_exp2f(x)
#else
#define EXP2F(x) __expf((x)*0.6931471805599453f)
#endif
// q pre-scale: HD^-0.5 * log2(e): scores come out of MFMA ready for exp2
#define QSCALE 0.18033688011112042f

__device__ __forceinline__ void gl_lds16(const u16* g, u16* l){
  __builtin_amdgcn_global_load_lds((gas_t)g, (las_t)l, 16, 0, 0);
}
__device__ __forceinline__ u16 f2bf(float f){
  unsigned u = __float_as_uint(f);
  u += 0x7FFF + ((u >> 16) & 1);      // RNE
  return (u16)(u >> 16);
}
__device__ __forceinline__ float bf2f(u16 h){
  return __uint_as_float(((unsigned)h) << 16);
}
__device__ __forceinline__ float dot4f(float4 a, float4 b){
  return a.x*b.x + a.y*b.y + a.z*b.z + a.w*b.w;
}

struct KArgs {
  const float *x, *Wq, *bq, *Wk, *bk, *Wv, *bv, *Wo, *bo;
  const float *dWk, *dbw, *dbb, *dWv, *dbv, *ln_g, *ln_b;
  float *out;
  u16 *xb, *dWkT, *kraw, *qk;
  float *wv, *cv, *Vw, *l_arr, *pv_arr;   // l_arr and pv_arr contiguous (MM*HH each)
};

// ---------------------------------------------------------------------------
// Phase 1 unit: convert x / transpose dWk / precompute wv,cv / zero l,pv
__device__ __forceinline__ void do_prep_unit(const KArgs& A, int blk, int t, float* redS) {
  if (blk < NB_CONV) {
    size_t idx = ((size_t)blk*256 + t)*8;
    float4 a = *(const float4*)(A.x + idx);
    float4 b = *(const float4*)(A.x + idx + 4);
    union { u16 u[8]; uint4 v; } pk;
    pk.u[0]=f2bf(a.x); pk.u[1]=f2bf(a.y); pk.u[2]=f2bf(a.z); pk.u[3]=f2bf(a.w);
    pk.u[4]=f2bf(b.x); pk.u[5]=f2bf(b.y); pk.u[6]=f2bf(b.z); pk.u[7]=f2bf(b.w);
    *(uint4*)(A.xb + idx) = pk.v;
    return;
  }
  blk -= NB_CONV;
  if (blk < NB_TRAN) {
    int xi = blk & 3, rest = blk >> 2;
    int ck = rest & 127, i = rest >> 7;
    int n  = xi*256 + t;
    const float* src = A.dWk + (size_t)i*DD*DD + (size_t)ck*8*DD + n;
    union { u16 u[8]; uint4 v; } pk;
    #pragma unroll
    for (int e=0;e<8;e++) pk.u[e] = f2bf(src[(size_t)e*DD]);
    *(uint4*)(A.dWkT + (size_t)i*DD*DD + (size_t)n*DD + ck*8) = pk.v;
    return;
  }
  blk -= NB_TRAN;
  if (blk < NB_PREC) {
    int i = blk / 1025, row = blk % 1025;
    const float* W    = (i==0)?A.Wq:(i==1)?A.Wk:(i==2)?A.Wv:A.Wo;
    const float* bvec = (i==0)?A.bq:(i==1)?A.bk:(i==2)?A.bv:A.bo;
    const float* s = A.dWv + i*DD;
    float acc = 0.f;
    if (row < DD) {
      const float* r = W + (size_t)row * DD;
      for (int e = t; e < DD; e += 256) acc += r[e]*s[e];
    } else {
      for (int e = t; e < DD; e += 256) acc += bvec[e]*s[e];
    }
    redS[t] = acc; __syncthreads();
    for (int off=128; off>0; off>>=1){ if(t<off) redS[t]+=redS[t+off]; __syncthreads(); }
    if (t==0) {
      if (row < DD) A.wv[i*DD + row] = redS[0];
      else          A.cv[i] = redS[0] + A.dbv[i];
    }
    __syncthreads();   // allow redS reuse by next unit
    return;
  }
  blk -= NB_PREC;
  {  // zero l/pv: 64 units x 256 thr x 8 floats = 131072 = l_arr + pv_arr
    size_t idx = ((size_t)blk*256 + t)*8;
    *(float4*)(A.l_arr + idx)     = make_float4(0.f,0.f,0.f,0.f);
    *(float4*)(A.l_arr + idx + 4) = make_float4(0.f,0.f,0.f,0.f);
  }
}

// ---------------------------------------------------------------------------
// Phase 2 unit: one 128x128x1024 MFMA GEMM tile (m97 structure)
__device__ __forceinline__ void do_gemm_unit(const KArgs& A, int u, int t, u16* SH) {
  u16* As = SH;
  u16* Bs = SH + 8192;
  const int i = u >> 8;
  const int n0 = (u & 7) * 128, m0 = ((u >> 3) & 31) * 128;
  const u16* Bm = A.dWkT + (size_t)i*DD*DD;
  u16* C = A.kraw + (size_t)i*MM*DD;
  const int w = t>>6, lane = t&63;
  const int q15 = lane&15, quad = lane>>4;
  const int wm = w>>1, wn = w&1;
  const int lr = lane>>3, lc = lane&7, gsw = lc ^ lr;
  const int sw = q15 & 7;
  f32x4 acc[4][4];
  #pragma unroll
  for(int a=0;a<4;a++)
    #pragma unroll
    for(int b2=0;b2<4;b2++) acc[a][b2] = (f32x4){0.f,0.f,0.f,0.f};

  for (int k0=0; k0<DD; k0+=64) {
    __syncthreads();
    #pragma unroll
    for (int j=0; j<4; j++) {
      int r = (w*4+j)*8 + lr;
      gl_lds16(A.xb + (size_t)(m0+r)*DD + k0 + gsw*8, &As[((w*4+j)*8)*64]);
      gl_lds16(Bm   + (size_t)(n0+r)*DD + k0 + gsw*8, &Bs[((w*4+j)*8)*64]);
    }
    __syncthreads();
    #pragma unroll
    for (int kk=0; kk<2; kk++) {
      bf16x8 af[4], bfr[4];
      #pragma unroll
      for (int mt=0; mt<4; mt++)
        af[mt]  = *(bf16x8*)(&As[(wm*64+mt*16+q15)*64 + ((kk*4+quad)^sw)*8]);
      #pragma unroll
      for (int nt=0; nt<4; nt++)
        bfr[nt] = *(bf16x8*)(&Bs[(wn*64+nt*16+q15)*64 + ((kk*4+quad)^sw)*8]);
      #pragma unroll
      for (int mt=0; mt<4; mt++)
        #pragma unroll
        for (int nt=0; nt<4; nt++)
          acc[mt][nt] = __builtin_amdgcn_mfma_f32_16x16x32_bf16(af[mt], bfr[nt], acc[mt][nt], 0,0,0);
    }
  }
  #pragma unroll
  for (int mt=0; mt<4; mt++)
    #pragma unroll
    for (int nt=0; nt<4; nt++)
      #pragma unroll
      for (int r=0; r<4; r++) {
        int m = m0 + wm*64 + mt*16 + quad*4 + r;
        int n = n0 + wn*64 + nt*16 + q15;
        C[(size_t)m*DD + n] = f2bf(acc[mt][nt][r]);
      }
}

// ---------------------------------------------------------------------------
// Phase 3 unit: delta i=0..2 for one token row -> q' (pre-scaled), k, Vw
__device__ __forceinline__ void do_delta_row(const KArgs& A, int m, int t, float4 (*part)[4]) {
  int w = t>>6, lane = t&63;
  const float* xr = A.x + (size_t)m*DD;
  float4 xv = *(const float4*)(xr + t*4);
  float4 kvs[3];
  #pragma unroll
  for (int i=0;i<3;i++) {
    ushort4 ku = *(const ushort4*)(A.kraw + (size_t)i*MM*DD + (size_t)m*DD + t*4);
    float4 kv = make_float4(bf2f(ku.x), bf2f(ku.y), bf2f(ku.z), bf2f(ku.w));
    kvs[i] = kv;
    float4 bwv = *(const float4*)(A.dbw + i*DD + t*4);
    float4 wvv = *(const float4*)(A.wv  + i*DD + t*4);
    float4 red = make_float4(dot4f(kv,kv), dot4f(kv,xv), dot4f(xv,bwv), dot4f(xv,wvv));
    #pragma unroll
    for (int off=32; off>0; off>>=1) {
      red.x += __shfl_xor(red.x, off);
      red.y += __shfl_xor(red.y, off);
      red.z += __shfl_xor(red.z, off);
      red.w += __shfl_xor(red.w, off);
    }
    if (lane==0) part[i][w] = red;
  }
  __syncthreads();
  float cc[3];
  #pragma unroll
  for (int i=0;i<3;i++) {
    float4 r0=part[i][0], r1=part[i][1], r2=part[i][2], r3=part[i][3];
    float s0=r0.x+r1.x+r2.x+r3.x, s1=r0.y+r1.y+r2.y+r3.y;
    float s2=r0.z+r1.z+r2.z+r3.z, s3=r0.w+r1.w+r2.w+r3.w;
    float nrmE = sqrtf(s0) + 1e-8f;
    float kdh  = s1 / nrmE;
    float beta = 2.f / (1.f + __expf(-(s2 + A.dbb[i])));
    float vs   = s3 + A.cv[i];
    cc[i] = beta * (vs - kdh) / nrmE;
  }
  {
    float c = cc[0]; float4 kv = kvs[0];
    ushort4 ou;
    ou.x = f2bf((xv.x + c*kv.x)*QSCALE); ou.y = f2bf((xv.y + c*kv.y)*QSCALE);
    ou.z = f2bf((xv.z + c*kv.z)*QSCALE); ou.w = f2bf((xv.w + c*kv.w)*QSCALE);
    *(ushort4*)(A.qk + (size_t)m*DD + t*4) = ou;
  }
  {
    float c = cc[1]; float4 kv = kvs[1];
    ushort4 ou;
    ou.x = f2bf(xv.x + c*kv.x); ou.y = f2bf(xv.y + c*kv.y);
    ou.z = f2bf(xv.z + c*kv.z); ou.w = f2bf(xv.w + c*kv.w);
    *(ushort4*)(A.qk + (size_t)MM*DD + (size_t)m*DD + t*4) = ou;
  }
  {
    float c = cc[2]; float4 kv = kvs[2];
    float4 vv = make_float4(xv.x + c*kv.x, xv.y + c*kv.y, xv.z + c*kv.z, xv.w + c*kv.w);
    float4 w3 = *(const float4*)(A.wv + 3*DD + t*4);
    float s = dot4f(vv, w3);
    #pragma unroll
    for (int off=1; off<16; off<<=1) s += __shfl_xor(s, off);
    if ((lane & 15) == 0) {
      int head = t >> 4;
      int b = m >> 11, srow = m & (SS-1);
      A.Vw[((size_t)(b*HH + head))*SS + srow] = s;
    }
  }
  __syncthreads();   // part reuse by next row
}

// ---------------------------------------------------------------------------
// Phase 4 unit: QK^T flash chunk (64 q x 1024 keys), double-buffered K DMA
__device__ __forceinline__ void do_flash_unit(const KArgs& A, int u, int t, u16* SH) {
  u16* Qs  = SH;          // 4096 u16
  u16* KsB = SH + 4096;   // 2 x 4096 u16
  const int qt = u & 31, h = (u >> 5) & 15, z = u >> 9;
  const int b = z >> 1, kc = z & 1;
  const int w = t>>6, lane = t&63, q15 = lane&15, quad = lane>>4;
  const int lr = lane>>3, lc = lane&7, gsw = lc ^ lr;
  const int sw = q15 & 7;
  const size_t hb = (size_t)h*HD;
  const u16* qb = A.qk;
  const u16* kbase = A.qk + (size_t)MM*DD + (size_t)(b*SS + kc*KT_PER*64)*DD + hb;
  const float* vwb = A.Vw + (size_t)(b*HH + h)*SS + kc*KT_PER*64;

  #pragma unroll
  for (int j=0; j<2; j++) {
    int r = (w*2+j)*8 + lr;
    gl_lds16(qb + (size_t)(b*SS + qt*64 + r)*DD + hb + gsw*8, &Qs[((w*2+j)*8)*64]);
    gl_lds16(kbase + (size_t)r*DD + gsw*8, &KsB[((w*2+j)*8)*64]);
  }
  float4 vwreg[4];
  #pragma unroll
  for (int rt=0; rt<4; rt++) vwreg[rt] = *(const float4*)(vwb + rt*16 + quad*4);

  float l_acc = 0.f, pv_acc = 0.f;
  __syncthreads();                              // Q + K0 staged
  bf16x8 qf[2];
  #pragma unroll
  for (int kk=0; kk<2; kk++)
    qf[kk] = *(bf16x8*)(&Qs[(w*16+q15)*64 + ((kk*4+quad)^sw)*8]);

  for (int kt=0; kt<KT_PER; kt++) {
    if (kt+1 < KT_PER) {
      #pragma unroll
      for (int j=0; j<2; j++) {
        int r = (w*2+j)*8 + lr;
        gl_lds16(kbase + (size_t)((kt+1)*64 + r)*DD + gsw*8,
                 &KsB[(((kt+1)&1)<<12) + ((w*2+j)*8)*64]);
      }
    }
    f32x4 Sacc[4];
    #pragma unroll
    for (int rt=0; rt<4; rt++) Sacc[rt] = (f32x4){0.f,0.f,0.f,0.f};
    #pragma unroll
    for (int kk=0; kk<2; kk++) {
      #pragma unroll
      for (int rt=0; rt<4; rt++) {
        bf16x8 kf = *(bf16x8*)(&KsB[((kt&1)<<12) + (rt*16+q15)*64 + ((kk*4+quad)^sw)*8]);
        Sacc[rt] = __builtin_amdgcn_mfma_f32_16x16x32_bf16(kf, qf[kk], Sacc[rt], 0,0,0);
      }
    }
    float4 vwcur[4];
    #pragma unroll
    for (int rt=0; rt<4; rt++) vwcur[rt] = vwreg[rt];
    if (kt+1 < KT_PER) {
      #pragma unroll
      for (int rt=0; rt<4; rt++)
        vwreg[rt] = *(const float4*)(vwb + (kt+1)*64 + rt*16 + quad*4);
    }
    #pragma unroll
    for (int rt=0; rt<4; rt++) {
      float va[4] = {vwcur[rt].x, vwcur[rt].y, vwcur[rt].z, vwcur[rt].w};
      #pragma unroll
      for (int r=0; r<4; r++) {
        float p = EXP2F(fminf(Sacc[rt][r], 30.f));
        l_acc  += p;
        pv_acc += p * va[r];
      }
    }
    __syncthreads();   // release Ks buffer for DMA; drain next DMA
  }
  l_acc  += __shfl_xor(l_acc, 16);  l_acc  += __shfl_xor(l_acc, 32);
  pv_acc += __shfl_xor(pv_acc, 16); pv_acc += __shfl_xor(pv_acc, 32);
  if (quad == 0) {
    int tok = b*SS + qt*64 + w*16 + q15;
    atomicAdd(&A.l_arr[(size_t)tok*HH + h],  l_acc);
    atomicAdd(&A.pv_arr[(size_t)tok*HH + h], pv_acc);
  }
}

// ---------------------------------------------------------------------------
// Phase 5 unit: delta #3 + LayerNorm for one token row
__device__ __forceinline__ void do_final_row(const KArgs& A, int m, int t,
                                             float4* part, float2* part2, float* v3sS) {
  int w = t>>6, lane = t&63;
  const float* xr = A.x + (size_t)m*DD;
  const u16*   kr = A.kraw + 3*(size_t)MM*DD + (size_t)m*DD;
  float4 xv  = *(const float4*)(xr + t*4);
  ushort4 ku = *(const ushort4*)(kr + t*4);
  float4 kv  = make_float4(bf2f(ku.x), bf2f(ku.y), bf2f(ku.z), bf2f(ku.w));
  float4 bwv = *(const float4*)(A.dbw + 3*DD + t*4);
  if (t < 16) {
    float val = A.pv_arr[(size_t)m*HH + t] / A.l_arr[(size_t)m*HH + t];
    #pragma unroll
    for (int off=1; off<16; off<<=1) val += __shfl_xor(val, off);
    if (t==0) *v3sS = val;
  }
  float4 red = make_float4(dot4f(kv,kv), dot4f(kv,xv), dot4f(xv,bwv), 0.f);
  #pragma unroll
  for (int off=32; off>0; off>>=1) {
    red.x += __shfl_xor(red.x, off);
    red.y += __shfl_xor(red.y, off);
    red.z += __shfl_xor(red.z, off);
  }
  if (lane==0) part[w] = red;
  __syncthreads();
  float4 r0=part[0], r1=part[1], r2=part[2], r3=part[3];
  float s0=r0.x+r1.x+r2.x+r3.x, s1=r0.y+r1.y+r2.y+r3.y, s2=r0.z+r1.z+r2.z+r3.z;
  float nrmE = sqrtf(s0) + 1e-8f;
  float kdh  = s1 / nrmE;
  float beta = 2.f / (1.f + __expf(-(s2 + A.dbb[3])));
  float v3   = *v3sS + A.cv[3];
  float c = beta * (v3 - kdh) / nrmE;
  float y0 = xv.x + c*kv.x, y1 = xv.y + c*kv.y, y2 = xv.z + c*kv.z, y3 = xv.w + c*kv.w;
  float2 rr = make_float2(y0+y1+y2+y3, y0*y0+y1*y1+y2*y2+y3*y3);
  #pragma unroll
  for (int off=32; off>0; off>>=1) {
    rr.x += __shfl_xor(rr.x, off);
    rr.y += __shfl_xor(rr.y, off);
  }
  if (lane==0) part2[w] = rr;
  __syncthreads();
  float ssum = part2[0].x+part2[1].x+part2[2].x+part2[3].x;
  float ssq  = part2[0].y+part2[1].y+part2[2].y+part2[3].y;
  float mu   = ssum * (1.f/DD);
  float var  = ssq * (1.f/DD) - mu*mu;
  float rstd = rsqrtf(var + 1e-5f);
  float4 g  = *(const float4*)(A.ln_g + t*4);
  float4 bb = *(const float4*)(A.ln_b + t*4);
  float4 ov;
  ov.x = (y0-mu)*rstd*g.x + bb.x;
  ov.y = (y1-mu)*rstd*g.y + bb.y;
  ov.z = (y2-mu)*rstd*g.z + bb.z;
  ov.w = (y3-mu)*rstd*g.w + bb.w;
  *(float4*)(A.out + (size_t)m*DD + t*4) = ov;
  __syncthreads();   // part/part2/v3s reuse by next row
}

// ---------------------------------------------------------------------------
// The persistent cooperative mega-kernel: all phases, grid.sync between them.
__global__ __launch_bounds__(256, 4) void mega_kernel(KArgs A) {
  cg::grid_group grid = cg::this_grid();
  __shared__ __align__(16) u16 SH[16384];     // 32 KB (gemm As/Bs | flash Qs/Ks)
  __shared__ float  redS[256];
  __shared__ float4 partS[3][4];
  __shared__ float2 part2S[4];
  __shared__ float  v3sS;
  const int t = threadIdx.x, g = gridDim.x, bid = blockIdx.x;

  for (int u = bid; u < NB_PREP;  u += g) do_prep_unit(A, u, t, redS);
  grid.sync();
  for (int u = bid; u < NB_GEMM;  u += g) do_gemm_unit(A, u, t, SH);
  grid.sync();
  for (int m = bid; m < MM;       m += g) do_delta_row(A, m, t, partS);
  grid.sync();
  for (int u = bid; u < NB_FLASH; u += g) do_flash_unit(A, u, t, SH);
  grid.sync();
  for (int m = bid; m < MM;       m += g) do_final_row(A, m, t, &partS[0][0], part2S, &v3sS);
}

// ---------------------------------------------------------------------------
// Fallback wrappers (plain launches) in case cooperative launch is refused.
__global__ void prep_wrap(KArgs A) {
  __shared__ float redS[256];
  do_prep_unit(A, blockIdx.x, threadIdx.x, redS);
}
__global__ __launch_bounds__(256) void gemm_wrap(KArgs A) {
  __shared__ __align__(16) u16 SH[16384];
  do_gemm_unit(A, blockIdx.x, threadIdx.x, SH);
}
__global__ void delta_wrap(KArgs A) {
  __shared__ float4 partS[3][4];
  do_delta_row(A, blockIdx.x, threadIdx.x, partS);
}
__global__ __launch_bounds__(256) void flash_wrap(KArgs A) {
  __shared__ __align__(16) u16 SH[12288];
  do_flash_unit(A, blockIdx.x, threadIdx.x, SH);
}
__global__ void final_wrap(KArgs A) {
  __shared__ float4 partS[4];
  __shared__ float2 part2S[4];
  __shared__ float  v3sS;
  do_final_row(A, blockIdx.x, threadIdx.x, partS, part2S, &v3sS);
}

// ---------------------------------------------------------------------------
extern "C" void kernel_launch(void* const* d_in, const int* in_sizes, int n_in,
                              void* d_out, int out_size, void* d_ws, size_t ws_size,
                              hipStream_t stream) {
  char* WS = (char*)d_ws;
  KArgs A;
  A.x    = (const float*)d_in[0];
  A.Wq   = (const float*)d_in[1];  A.bq = (const float*)d_in[2];
  A.Wk   = (const float*)d_in[3];  A.bk = (const float*)d_in[4];
  A.Wv   = (const float*)d_in[5];  A.bv = (const float*)d_in[6];
  A.Wo   = (const float*)d_in[7];  A.bo = (const float*)d_in[8];
  A.dWk  = (const float*)d_in[9];
  A.dbw  = (const float*)d_in[10]; A.dbb = (const float*)d_in[11];
  A.dWv  = (const float*)d_in[12]; A.dbv = (const float*)d_in[13];
  A.ln_g = (const float*)d_in[14]; A.ln_b = (const float*)d_in[15];
  A.out  = (float*)d_out;

  // workspace layout (bytes):
  A.wv    = (float*)WS;                                   // 16 KB
  A.cv    = (float*)(WS + 16384);                         // 256 B
  A.kraw  = (u16*)  (WS + 16640);                         // 4*MM*DD bf16 = 33.5 MB
  A.qk    = (u16*)  (WS + 16640 + (size_t)4*MM*DD*2);     // 2*MM*DD bf16 = 16.8 MB
  A.dWkT  = (u16*)  (WS + 16640 + (size_t)6*MM*DD*2);     // 8.4 MB
  A.xb    = (u16*)  (WS + 16640 + (size_t)6*MM*DD*2 + (size_t)4*DD*DD*2); // 8.4 MB
  char* tail = WS + 16640 + (size_t)6*MM*DD*2 + (size_t)8*DD*DD*2;
  A.Vw     = (float*)tail;                                // 256 KB
  A.l_arr  = (float*)(tail + (size_t)BB*HH*SS*4);         // 256 KB
  A.pv_arr = (float*)(tail + (size_t)BB*HH*SS*4 + (size_t)MM*HH*4); // 256 KB (contiguous after l_arr)

  bool coop_ok = false;
  int nb = 0;
  hipError_t oe = hipOccupancyMaxActiveBlocksPerMultiprocessor(&nb, mega_kernel, 256, 0);
  if (oe == hipSuccess && nb > 0) {
    int grid = nb * 256;            // 256 CUs on MI355X
    if (grid > 1024) grid = 1024;   // max useful (gemm phase has 1024 units)
    KArgs ha = A;
    void* args[] = { &ha };
    hipError_t le = hipLaunchCooperativeKernel(mega_kernel, dim3(grid), dim3(256),
                                               args, 0, stream);
    coop_ok = (le == hipSuccess);
    if (!coop_ok) (void)hipGetLastError();
  }
  if (!coop_ok) {
    prep_wrap <<<NB_PREP,  256, 0, stream>>>(A);
    gemm_wrap <<<NB_GEMM,  256, 0, stream>>>(A);
    delta_wrap<<<MM,       256, 0, stream>>>(A);
    flash_wrap<<<NB_FLASH, 256, 0, stream>>>(A);
    final_wrap<<<MM,       256, 0, stream>>>(A);
  }
}

// Round 7
// 529.257 us; speedup vs baseline: 1.0254x; 1.0254x over previous
//
#include <hip/hip_runtime.h>
#include <hip/hip_cooperative_groups.h>

namespace cg = cooperative_groups;

#define BB 2
#define SS 2048
#define DD 1024
#define HH 16
#define HD 64
#define MM (BB*SS)   // 4096
#define KC 2                 // flash split-K chunks
#define KT_PER (SS/64/KC)    // 16 tiles per chunk

#define NB_CONV 2048
#define NB_TRAN 2048
#define NB_PREC 4100
#define NB_PREP (NB_CONV+NB_TRAN+NB_PREC)
#define NB_GEMM 1024
#define NB_FLASH (32*HH*BB*KC)   // 2048

typedef unsigned short u16;
typedef __attribute__((ext_vector_type(8))) short bf16x8;
typedef __attribute__((ext_vector_type(4))) float f32x4;

typedef __attribute__((address_space(1))) const unsigned int* gas_t;
typedef __attribute__((address_space(3))) unsigned int* las_t;

#ifndef __has_builtin
#define __has_builtin(x) 0
#endif
#if __has_builtin(__builtin_amdgcn_exp2f)
#define EXP2F(x) __builtin_amdgcn_exp2f(x)
#else
#define EXP2F(x) __expf((x)*0.6931471805599453f)
#endif
// q pre-scale: HD^-0.5 * log2(e): scores come out of MFMA ready for exp2
#define QSCALE 0.18033688011112042f

__device__ __forceinline__ void gl_lds16(const u16* g, u16* l){
  __builtin_amdgcn_global_load_lds((gas_t)g, (las_t)l, 16, 0, 0);
}
__device__ __forceinline__ u16 f2bf(float f){
  unsigned u = __float_as_uint(f);
  u += 0x7FFF + ((u >> 16) & 1);      // RNE
  return (u16)(u >> 16);
}
__device__ __forceinline__ float bf2f(u16 h){
  return __uint_as_float(((unsigned)h) << 16);
}
__device__ __forceinline__ float dot4f(float4 a, float4 b){
  return a.x*b.x + a.y*b.y + a.z*b.z + a.w*b.w;
}

struct KArgs {
  const float *x, *Wq, *bq, *Wk, *bk, *Wv, *bv, *Wo, *bo;
  const float *dWk, *dbw, *dbb, *dWv, *dbv, *ln_g, *ln_b;
  float *out;
  u16 *xb, *dWkT, *kraw, *qk;
  float *wv, *cv, *Vw, *l_arr, *pv_arr;   // l/pv: [KC][MM][HH] plain-store slabs
};

// ---------------------------------------------------------------------------
// Phase 1 unit: convert x / transpose dWk / precompute wv,cv
__device__ __forceinline__ void do_prep_unit(const KArgs& A, int blk, int t, float* redS) {
  if (blk < NB_CONV) {
    size_t idx = ((size_t)blk*256 + t)*8;
    float4 a = *(const float4*)(A.x + idx);
    float4 b = *(const float4*)(A.x + idx + 4);
    union { u16 u[8]; uint4 v; } pk;
    pk.u[0]=f2bf(a.x); pk.u[1]=f2bf(a.y); pk.u[2]=f2bf(a.z); pk.u[3]=f2bf(a.w);
    pk.u[4]=f2bf(b.x); pk.u[5]=f2bf(b.y); pk.u[6]=f2bf(b.z); pk.u[7]=f2bf(b.w);
    *(uint4*)(A.xb + idx) = pk.v;
    return;
  }
  blk -= NB_CONV;
  if (blk < NB_TRAN) {
    int xi = blk & 3, rest = blk >> 2;
    int ck = rest & 127, i = rest >> 7;
    int n  = xi*256 + t;
    const float* src = A.dWk + (size_t)i*DD*DD + (size_t)ck*8*DD + n;
    union { u16 u[8]; uint4 v; } pk;
    #pragma unroll
    for (int e=0;e<8;e++) pk.u[e] = f2bf(src[(size_t)e*DD]);
    *(uint4*)(A.dWkT + (size_t)i*DD*DD + (size_t)n*DD + ck*8) = pk.v;
    return;
  }
  blk -= NB_TRAN;
  {
    int i = blk / 1025, row = blk % 1025;
    const float* W    = (i==0)?A.Wq:(i==1)?A.Wk:(i==2)?A.Wv:A.Wo;
    const float* bvec = (i==0)?A.bq:(i==1)?A.bk:(i==2)?A.bv:A.bo;
    const float* s = A.dWv + i*DD;
    float acc = 0.f;
    if (row < DD) {
      const float* r = W + (size_t)row * DD;
      for (int e = t; e < DD; e += 256) acc += r[e]*s[e];
    } else {
      for (int e = t; e < DD; e += 256) acc += bvec[e]*s[e];
    }
    redS[t] = acc; __syncthreads();
    for (int off=128; off>0; off>>=1){ if(t<off) redS[t]+=redS[t+off]; __syncthreads(); }
    if (t==0) {
      if (row < DD) A.wv[i*DD + row] = redS[0];
      else          A.cv[i] = redS[0] + A.dbv[i];
    }
    __syncthreads();   // allow redS reuse by next unit
  }
}

// ---------------------------------------------------------------------------
// Phase 2 unit: one 128x128x1024 MFMA GEMM tile (m97 structure)
__device__ __forceinline__ void do_gemm_unit(const KArgs& A, int u, int t, u16* SH) {
  u16* As = SH;
  u16* Bs = SH + 8192;
  const int i = u >> 8;
  const int n0 = (u & 7) * 128, m0 = ((u >> 3) & 31) * 128;
  const u16* Bm = A.dWkT + (size_t)i*DD*DD;
  u16* C = A.kraw + (size_t)i*MM*DD;
  const int w = t>>6, lane = t&63;
  const int q15 = lane&15, quad = lane>>4;
  const int wm = w>>1, wn = w&1;
  const int lr = lane>>3, lc = lane&7, gsw = lc ^ lr;
  const int sw = q15 & 7;
  f32x4 acc[4][4];
  #pragma unroll
  for(int a=0;a<4;a++)
    #pragma unroll
    for(int b2=0;b2<4;b2++) acc[a][b2] = (f32x4){0.f,0.f,0.f,0.f};

  for (int k0=0; k0<DD; k0+=64) {
    __syncthreads();
    #pragma unroll
    for (int j=0; j<4; j++) {
      int r = (w*4+j)*8 + lr;
      gl_lds16(A.xb + (size_t)(m0+r)*DD + k0 + gsw*8, &As[((w*4+j)*8)*64]);
      gl_lds16(Bm   + (size_t)(n0+r)*DD + k0 + gsw*8, &Bs[((w*4+j)*8)*64]);
    }
    __syncthreads();
    #pragma unroll
    for (int kk=0; kk<2; kk++) {
      bf16x8 af[4], bfr[4];
      #pragma unroll
      for (int mt=0; mt<4; mt++)
        af[mt]  = *(bf16x8*)(&As[(wm*64+mt*16+q15)*64 + ((kk*4+quad)^sw)*8]);
      #pragma unroll
      for (int nt=0; nt<4; nt++)
        bfr[nt] = *(bf16x8*)(&Bs[(wn*64+nt*16+q15)*64 + ((kk*4+quad)^sw)*8]);
      #pragma unroll
      for (int mt=0; mt<4; mt++)
        #pragma unroll
        for (int nt=0; nt<4; nt++)
          acc[mt][nt] = __builtin_amdgcn_mfma_f32_16x16x32_bf16(af[mt], bfr[nt], acc[mt][nt], 0,0,0);
    }
  }
  #pragma unroll
  for (int mt=0; mt<4; mt++)
    #pragma unroll
    for (int nt=0; nt<4; nt++)
      #pragma unroll
      for (int r=0; r<4; r++) {
        int m = m0 + wm*64 + mt*16 + quad*4 + r;
        int n = n0 + wn*64 + nt*16 + q15;
        C[(size_t)m*DD + n] = f2bf(acc[mt][nt][r]);
      }
}

// ---------------------------------------------------------------------------
// Phase 3 unit: delta i=0..2 for one token row -> q' (pre-scaled), k, Vw
__device__ __forceinline__ void do_delta_row(const KArgs& A, int m, int t, float4 (*part)[4]) {
  int w = t>>6, lane = t&63;
  const float* xr = A.x + (size_t)m*DD;
  float4 xv = *(const float4*)(xr + t*4);
  float4 kvs[3];
  #pragma unroll
  for (int i=0;i<3;i++) {
    ushort4 ku = *(const ushort4*)(A.kraw + (size_t)i*MM*DD + (size_t)m*DD + t*4);
    float4 kv = make_float4(bf2f(ku.x), bf2f(ku.y), bf2f(ku.z), bf2f(ku.w));
    kvs[i] = kv;
    float4 bwv = *(const float4*)(A.dbw + i*DD + t*4);
    float4 wvv = *(const float4*)(A.wv  + i*DD + t*4);
    float4 red = make_float4(dot4f(kv,kv), dot4f(kv,xv), dot4f(xv,bwv), dot4f(xv,wvv));
    #pragma unroll
    for (int off=32; off>0; off>>=1) {
      red.x += __shfl_xor(red.x, off);
      red.y += __shfl_xor(red.y, off);
      red.z += __shfl_xor(red.z, off);
      red.w += __shfl_xor(red.w, off);
    }
    if (lane==0) part[i][w] = red;
  }
  __syncthreads();
  float cc[3];
  #pragma unroll
  for (int i=0;i<3;i++) {
    float4 r0=part[i][0], r1=part[i][1], r2=part[i][2], r3=part[i][3];
    float s0=r0.x+r1.x+r2.x+r3.x, s1=r0.y+r1.y+r2.y+r3.y;
    float s2=r0.z+r1.z+r2.z+r3.z, s3=r0.w+r1.w+r2.w+r3.w;
    float nrmE = sqrtf(s0) + 1e-8f;
    float kdh  = s1 / nrmE;
    float beta = 2.f / (1.f + __expf(-(s2 + A.dbb[i])));
    float vs   = s3 + A.cv[i];
    cc[i] = beta * (vs - kdh) / nrmE;
  }
  {
    float c = cc[0]; float4 kv = kvs[0];
    ushort4 ou;
    ou.x = f2bf((xv.x + c*kv.x)*QSCALE); ou.y = f2bf((xv.y + c*kv.y)*QSCALE);
    ou.z = f2bf((xv.z + c*kv.z)*QSCALE); ou.w = f2bf((xv.w + c*kv.w)*QSCALE);
    *(ushort4*)(A.qk + (size_t)m*DD + t*4) = ou;
  }
  {
    float c = cc[1]; float4 kv = kvs[1];
    ushort4 ou;
    ou.x = f2bf(xv.x + c*kv.x); ou.y = f2bf(xv.y + c*kv.y);
    ou.z = f2bf(xv.z + c*kv.z); ou.w = f2bf(xv.w + c*kv.w);
    *(ushort4*)(A.qk + (size_t)MM*DD + (size_t)m*DD + t*4) = ou;
  }
  {
    float c = cc[2]; float4 kv = kvs[2];
    float4 vv = make_float4(xv.x + c*kv.x, xv.y + c*kv.y, xv.z + c*kv.z, xv.w + c*kv.w);
    float4 w3 = *(const float4*)(A.wv + 3*DD + t*4);
    float s = dot4f(vv, w3);
    #pragma unroll
    for (int off=1; off<16; off<<=1) s += __shfl_xor(s, off);
    if ((lane & 15) == 0) {
      int head = t >> 4;
      int b = m >> 11, srow = m & (SS-1);
      A.Vw[((size_t)(b*HH + head))*SS + srow] = s;
    }
  }
  __syncthreads();   // part reuse by next row
}

// ---------------------------------------------------------------------------
// Phase 4 unit: QK^T flash chunk (64 q x 1024 keys), double-buffered K DMA.
// Plain stores into per-kc slabs (no atomics, no zero-init needed).
__device__ __forceinline__ void do_flash_unit(const KArgs& A, int u, int t, u16* SH) {
  u16* Qs  = SH;          // 4096 u16
  u16* KsB = SH + 4096;   // 2 x 4096 u16
  const int qt = u & 31, h = (u >> 5) & 15, z = u >> 9;
  const int b = z >> 1, kc = z & 1;
  const int w = t>>6, lane = t&63, q15 = lane&15, quad = lane>>4;
  const int lr = lane>>3, lc = lane&7, gsw = lc ^ lr;
  const int sw = q15 & 7;
  const size_t hb = (size_t)h*HD;
  const u16* qb = A.qk;
  const u16* kbase = A.qk + (size_t)MM*DD + (size_t)(b*SS + kc*KT_PER*64)*DD + hb;
  const float* vwb = A.Vw + (size_t)(b*HH + h)*SS + kc*KT_PER*64;

  #pragma unroll
  for (int j=0; j<2; j++) {
    int r = (w*2+j)*8 + lr;
    gl_lds16(qb + (size_t)(b*SS + qt*64 + r)*DD + hb + gsw*8, &Qs[((w*2+j)*8)*64]);
    gl_lds16(kbase + (size_t)r*DD + gsw*8, &KsB[((w*2+j)*8)*64]);
  }
  float4 vwreg[4];
  #pragma unroll
  for (int rt=0; rt<4; rt++) vwreg[rt] = *(const float4*)(vwb + rt*16 + quad*4);

  float l_acc = 0.f, pv_acc = 0.f;
  __syncthreads();                              // Q + K0 staged
  bf16x8 qf[2];
  #pragma unroll
  for (int kk=0; kk<2; kk++)
    qf[kk] = *(bf16x8*)(&Qs[(w*16+q15)*64 + ((kk*4+quad)^sw)*8]);

  for (int kt=0; kt<KT_PER; kt++) {
    if (kt+1 < KT_PER) {
      #pragma unroll
      for (int j=0; j<2; j++) {
        int r = (w*2+j)*8 + lr;
        gl_lds16(kbase + (size_t)((kt+1)*64 + r)*DD + gsw*8,
                 &KsB[(((kt+1)&1)<<12) + ((w*2+j)*8)*64]);
      }
    }
    f32x4 Sacc[4];
    #pragma unroll
    for (int rt=0; rt<4; rt++) Sacc[rt] = (f32x4){0.f,0.f,0.f,0.f};
    #pragma unroll
    for (int kk=0; kk<2; kk++) {
      #pragma unroll
      for (int rt=0; rt<4; rt++) {
        bf16x8 kf = *(bf16x8*)(&KsB[((kt&1)<<12) + (rt*16+q15)*64 + ((kk*4+quad)^sw)*8]);
        Sacc[rt] = __builtin_amdgcn_mfma_f32_16x16x32_bf16(kf, qf[kk], Sacc[rt], 0,0,0);
      }
    }
    float4 vwcur[4];
    #pragma unroll
    for (int rt=0; rt<4; rt++) vwcur[rt] = vwreg[rt];
    if (kt+1 < KT_PER) {
      #pragma unroll
      for (int rt=0; rt<4; rt++)
        vwreg[rt] = *(const float4*)(vwb + (kt+1)*64 + rt*16 + quad*4);
    }
    #pragma unroll
    for (int rt=0; rt<4; rt++) {
      float va[4] = {vwcur[rt].x, vwcur[rt].y, vwcur[rt].z, vwcur[rt].w};
      #pragma unroll
      for (int r=0; r<4; r++) {
        float p = EXP2F(fminf(Sacc[rt][r], 30.f));
        l_acc  += p;
        pv_acc += p * va[r];
      }
    }
    __syncthreads();   // release Ks buffer for DMA; drain next DMA
  }
  l_acc  += __shfl_xor(l_acc, 16);  l_acc  += __shfl_xor(l_acc, 32);
  pv_acc += __shfl_xor(pv_acc, 16); pv_acc += __shfl_xor(pv_acc, 32);
  if (quad == 0) {
    int tok = b*SS + qt*64 + w*16 + q15;
    size_t idx = (size_t)kc*MM*HH + (size_t)tok*HH + h;
    A.l_arr[idx]  = l_acc;
    A.pv_arr[idx] = pv_acc;
  }
}

// ---------------------------------------------------------------------------
// Phase 5 unit: delta #3 + LayerNorm for one token row
__device__ __forceinline__ void do_final_row(const KArgs& A, int m, int t,
                                             float4* part, float2* part2, float* v3sS) {
  int w = t>>6, lane = t&63;
  const float* xr = A.x + (size_t)m*DD;
  const u16*   kr = A.kraw + 3*(size_t)MM*DD + (size_t)m*DD;
  float4 xv  = *(const float4*)(xr + t*4);
  ushort4 ku = *(const ushort4*)(kr + t*4);
  float4 kv  = make_float4(bf2f(ku.x), bf2f(ku.y), bf2f(ku.z), bf2f(ku.w));
  float4 bwv = *(const float4*)(A.dbw + 3*DD + t*4);
  if (t < 16) {
    size_t i0 = (size_t)m*HH + t;
    float l0 = A.l_arr[i0],  l1 = A.l_arr[(size_t)MM*HH + i0];
    float p0 = A.pv_arr[i0], p1 = A.pv_arr[(size_t)MM*HH + i0];
    float val = (p0 + p1) / (l0 + l1);
    #pragma unroll
    for (int off=1; off<16; off<<=1) val += __shfl_xor(val, off);
    if (t==0) *v3sS = val;
  }
  float4 red = make_float4(dot4f(kv,kv), dot4f(kv,xv), dot4f(xv,bwv), 0.f);
  #pragma unroll
  for (int off=32; off>0; off>>=1) {
    red.x += __shfl_xor(red.x, off);
    red.y += __shfl_xor(red.y, off);
    red.z += __shfl_xor(red.z, off);
  }
  if (lane==0) part[w] = red;
  __syncthreads();
  float4 r0=part[0], r1=part[1], r2=part[2], r3=part[3];
  float s0=r0.x+r1.x+r2.x+r3.x, s1=r0.y+r1.y+r2.y+r3.y, s2=r0.z+r1.z+r2.z+r3.z;
  float nrmE = sqrtf(s0) + 1e-8f;
  float kdh  = s1 / nrmE;
  float beta = 2.f / (1.f + __expf(-(s2 + A.dbb[3])));
  float v3   = *v3sS + A.cv[3];
  float c = beta * (v3 - kdh) / nrmE;
  float y0 = xv.x + c*kv.x, y1 = xv.y + c*kv.y, y2 = xv.z + c*kv.z, y3 = xv.w + c*kv.w;
  float2 rr = make_float2(y0+y1+y2+y3, y0*y0+y1*y1+y2*y2+y3*y3);
  #pragma unroll
  for (int off=32; off>0; off>>=1) {
    rr.x += __shfl_xor(rr.x, off);
    rr.y += __shfl_xor(rr.y, off);
  }
  if (lane==0) part2[w] = rr;
  __syncthreads();
  float ssum = part2[0].x+part2[1].x+part2[2].x+part2[3].x;
  float ssq  = part2[0].y+part2[1].y+part2[2].y+part2[3].y;
  float mu   = ssum * (1.f/DD);
  float var  = ssq * (1.f/DD) - mu*mu;
  float rstd = rsqrtf(var + 1e-5f);
  float4 g  = *(const float4*)(A.ln_g + t*4);
  float4 bb = *(const float4*)(A.ln_b + t*4);
  float4 ov;
  ov.x = (y0-mu)*rstd*g.x + bb.x;
  ov.y = (y1-mu)*rstd*g.y + bb.y;
  ov.z = (y2-mu)*rstd*g.z + bb.z;
  ov.w = (y3-mu)*rstd*g.w + bb.w;
  *(float4*)(A.out + (size_t)m*DD + t*4) = ov;
  __syncthreads();   // part/part2/v3s reuse by next row
}

// ---------------------------------------------------------------------------
// Persistent cooperative mega-kernel. waves_per_eu(4,4) PINS the register
// allocator at the 4-waves/EU operating point (VGPR budget 128): round-6
// showed the compiler voluntarily chasing 8 waves/EU (VGPR=64) and spilling
// the MFMA accumulators to scratch (+68 MB HBM traffic, 657 us).
__global__ __attribute__((amdgpu_flat_work_group_size(256,256)))
           __attribute__((amdgpu_waves_per_eu(4,4)))
void mega_kernel(KArgs A) {
  cg::grid_group grid = cg::this_grid();
  __shared__ __align__(16) u16 SH[16384];     // 32 KB (gemm As/Bs | flash Qs/Ks)
  __shared__ float  redS[256];
  __shared__ float4 partS[3][4];
  __shared__ float2 part2S[4];
  __shared__ float  v3sS;
  const int t = threadIdx.x, g = gridDim.x, bid = blockIdx.x;

  for (int u = bid; u < NB_PREP;  u += g) do_prep_unit(A, u, t, redS);
  grid.sync();
  for (int u = bid; u < NB_GEMM;  u += g) do_gemm_unit(A, u, t, SH);
  grid.sync();
  for (int m = bid; m < MM;       m += g) do_delta_row(A, m, t, partS);
  grid.sync();
  for (int u = bid; u < NB_FLASH; u += g) do_flash_unit(A, u, t, SH);
  grid.sync();
  for (int m = bid; m < MM;       m += g) do_final_row(A, m, t, &partS[0][0], part2S, &v3sS);
}

// ---------------------------------------------------------------------------
// Fallback wrappers (plain launches) in case cooperative launch is refused.
__global__ void prep_wrap(KArgs A) {
  __shared__ float redS[256];
  do_prep_unit(A, blockIdx.x, threadIdx.x, redS);
}
__global__ __launch_bounds__(256) void gemm_wrap(KArgs A) {
  __shared__ __align__(16) u16 SH[16384];
  do_gemm_unit(A, blockIdx.x, threadIdx.x, SH);
}
__global__ void delta_wrap(KArgs A) {
  __shared__ float4 partS[3][4];
  do_delta_row(A, blockIdx.x, threadIdx.x, partS);
}
__global__ __launch_bounds__(256) void flash_wrap(KArgs A) {
  __shared__ __align__(16) u16 SH[12288];
  do_flash_unit(A, blockIdx.x, threadIdx.x, SH);
}
__global__ void final_wrap(KArgs A) {
  __shared__ float4 partS[4];
  __shared__ float2 part2S[4];
  __shared__ float  v3sS;
  do_final_row(A, blockIdx.x, threadIdx.x, partS, part2S, &v3sS);
}

// ---------------------------------------------------------------------------
extern "C" void kernel_launch(void* const* d_in, const int* in_sizes, int n_in,
                              void* d_out, int out_size, void* d_ws, size_t ws_size,
                              hipStream_t stream) {
  char* WS = (char*)d_ws;
  KArgs A;
  A.x    = (const float*)d_in[0];
  A.Wq   = (const float*)d_in[1];  A.bq = (const float*)d_in[2];
  A.Wk   = (const float*)d_in[3];  A.bk = (const float*)d_in[4];
  A.Wv   = (const float*)d_in[5];  A.bv = (const float*)d_in[6];
  A.Wo   = (const float*)d_in[7];  A.bo = (const float*)d_in[8];
  A.dWk  = (const float*)d_in[9];
  A.dbw  = (const float*)d_in[10]; A.dbb = (const float*)d_in[11];
  A.dWv  = (const float*)d_in[12]; A.dbv = (const float*)d_in[13];
  A.ln_g = (const float*)d_in[14]; A.ln_b = (const float*)d_in[15];
  A.out  = (float*)d_out;

  // workspace layout (bytes):
  A.wv    = (float*)WS;                                   // 16 KB
  A.cv    = (float*)(WS + 16384);                         // 256 B
  A.kraw  = (u16*)  (WS + 16640);                         // 4*MM*DD bf16 = 33.5 MB
  A.qk    = (u16*)  (WS + 16640 + (size_t)4*MM*DD*2);     // 2*MM*DD bf16 = 16.8 MB
  A.dWkT  = (u16*)  (WS + 16640 + (size_t)6*MM*DD*2);     // 8.4 MB
  A.xb    = (u16*)  (WS + 16640 + (size_t)6*MM*DD*2 + (size_t)4*DD*DD*2); // 8.4 MB
  char* tail = WS + 16640 + (size_t)6*MM*DD*2 + (size_t)8*DD*DD*2;
  A.Vw     = (float*)tail;                                          // 256 KB
  A.l_arr  = (float*)(tail + (size_t)BB*HH*SS*4);                   // KC*MM*HH = 512 KB
  A.pv_arr = (float*)(tail + (size_t)BB*HH*SS*4 + (size_t)KC*MM*HH*4); // 512 KB

  bool coop_ok = false;
  int nb = 0;
  hipError_t oe = hipOccupancyMaxActiveBlocksPerMultiprocessor(&nb, mega_kernel, 256, 0);
  if (oe == hipSuccess && nb > 0) {
    int grid = nb * 256;            // 256 CUs on MI355X
    if (grid > 1024) grid = 1024;   // gemm phase has 1024 units
    KArgs ha = A;
    void* args[] = { &ha };
    hipError_t le = hipLaunchCooperativeKernel(mega_kernel, dim3(grid), dim3(256),
                                               args, 0, stream);
    coop_ok = (le == hipSuccess);
    if (!coop_ok) (void)hipGetLastError();
  }
  if (!coop_ok) {
    prep_wrap <<<NB_PREP,  256, 0, stream>>>(A);
    gemm_wrap <<<NB_GEMM,  256, 0, stream>>>(A);
    delta_wrap<<<MM,       256, 0, stream>>>(A);
    flash_wrap<<<NB_FLASH, 256, 0, stream>>>(A);
    final_wrap<<<MM,       256, 0, stream>>>(A);
  }
}

// Round 8
// 234.353 us; speedup vs baseline: 2.3158x; 2.2584x over previous
//
#include <hip/hip_runtime.h>

#define BB 2
#define SS 2048
#define DD 1024
#define HH 16
#define HD 64
#define MM (BB*SS)   // 4096
#define KC 4                 // flash split-K chunks
#define KT_PER (SS/64/KC)    // 8 tiles per chunk

typedef unsigned short u16;
typedef __attribute__((ext_vector_type(8))) short bf16x8;
typedef __attribute__((ext_vector_type(4))) float f32x4;

typedef __attribute__((address_space(1))) const unsigned int* gas_t;
typedef __attribute__((address_space(3))) unsigned int* las_t;

#ifndef __has_builtin
#define __has_builtin(x) 0
#endif
#if __has_builtin(__builtin_amdgcn_exp2f)
#define EXP2F(x) __builtin_amdgcn_exp2f(x)
#else
#define EXP2F(x) __expf((x)*0.6931471805599453f)
#endif
// q pre-scale: HD^-0.5 * log2(e): scores come out of MFMA ready for exp2
#define QSCALE 0.18033688011112042f

__device__ __forceinline__ void gl_lds16(const u16* g, u16* l){
  __builtin_amdgcn_global_load_lds((gas_t)g, (las_t)l, 16, 0, 0);
}

__device__ __forceinline__ u16 f2bf(float f){
  unsigned u = __float_as_uint(f);
  u += 0x7FFF + ((u >> 16) & 1);      // RNE
  return (u16)(u >> 16);
}
__device__ __forceinline__ float bf2f(u16 h){
  return __uint_as_float(((unsigned)h) << 16);
}
__device__ __forceinline__ float dot4f(float4 a, float4 b){
  return a.x*b.x + a.y*b.y + a.z*b.z + a.w*b.w;
}

// ---------------------------------------------------------------------------
// Kernel 1 (fused prologue), 1-D grid of 8196 blocks:
//  [0,2048)      convert x -> xb (bf16)
//  [2048,4096)   transpose dWk -> dWkT (bf16 [i][n][k])
//  [4096,8196)   precompute wv[i][:], cv[i]
#define NB_CONV 2048
#define NB_TRAN 2048
#define NB_PREC 4100
#define NB_PREP (NB_CONV+NB_TRAN+NB_PREC)
__global__ void prep_kernel(const float* __restrict__ x, u16* __restrict__ xb,
                            const float* __restrict__ dWk, u16* __restrict__ dWkT,
                            const float* __restrict__ Wq_, const float* __restrict__ bq_,
                            const float* __restrict__ Wk_, const float* __restrict__ bk_,
                            const float* __restrict__ Wv_, const float* __restrict__ bv_,
                            const float* __restrict__ Wo_, const float* __restrict__ bo_,
                            const float* __restrict__ dWv, const float* __restrict__ dbv,
                            float* __restrict__ wv, float* __restrict__ cv) {
  int blk = blockIdx.x, t = threadIdx.x;
  if (blk < NB_CONV) {
    size_t idx = ((size_t)blk*256 + t)*8;
    float4 a = *(const float4*)(x + idx);
    float4 b = *(const float4*)(x + idx + 4);
    union { u16 u[8]; uint4 v; } pk;
    pk.u[0]=f2bf(a.x); pk.u[1]=f2bf(a.y); pk.u[2]=f2bf(a.z); pk.u[3]=f2bf(a.w);
    pk.u[4]=f2bf(b.x); pk.u[5]=f2bf(b.y); pk.u[6]=f2bf(b.z); pk.u[7]=f2bf(b.w);
    *(uint4*)(xb + idx) = pk.v;
    return;
  }
  blk -= NB_CONV;
  if (blk < NB_TRAN) {
    int xi = blk & 3, rest = blk >> 2;       // xi: n-block, rest: ck + 128*i
    int ck = rest & 127, i = rest >> 7;
    int n  = xi*256 + t;
    const float* src = dWk + (size_t)i*DD*DD + (size_t)ck*8*DD + n;
    union { u16 u[8]; uint4 v; } pk;
    #pragma unroll
    for (int e=0;e<8;e++) pk.u[e] = f2bf(src[(size_t)e*DD]);
    *(uint4*)(dWkT + (size_t)i*DD*DD + (size_t)n*DD + ck*8) = pk.v;
    return;
  }
  blk -= NB_TRAN;
  {
    int i = blk / 1025, row = blk % 1025;
    const float* W    = (i==0)?Wq_:(i==1)?Wk_:(i==2)?Wv_:Wo_;
    const float* bvec = (i==0)?bq_:(i==1)?bk_:(i==2)?bv_:bo_;
    const float* s = dWv + i*DD;
    __shared__ float red[256];
    float acc = 0.f;
    if (row < DD) {
      const float* r = W + (size_t)row * DD;
      for (int e = t; e < DD; e += 256) acc += r[e]*s[e];
    } else {
      for (int e = t; e < DD; e += 256) acc += bvec[e]*s[e];
    }
    red[t] = acc; __syncthreads();
    for (int off=128; off>0; off>>=1){ if(t<off) red[t]+=red[t+off]; __syncthreads(); }
    if (t==0) {
      if (row < DD) wv[i*DD + row] = red[0];
      else          cv[i] = red[0] + dbv[i];
    }
  }
}

// ---------------------------------------------------------------------------
// Kernel 2: kraw[i] = x @ dWk[i], bf16 MFMA (m97 structure), 1-D grid 1024.
// XCD-rectangle swizzle: linear block id round-robins XCDs (id&7 = XCD);
// give each XCD an 8m x 4n x 4i rectangle so its L2 re-serves the tiles:
// xb fetched 2x (2 n-groups) + dWkT 4x (4 m-groups) ~= 50 MB vs 78 MB before.
__global__ __launch_bounds__(256) void gemm_dwk_mfma(const u16* __restrict__ xb,
                          const u16* __restrict__ Bt, u16* __restrict__ kraw) {
  const int id = blockIdx.x;
  const int xcd = id & 7, j = id >> 3;
  const int i = j & 3, rest = j >> 2;
  const int mloc = rest & 7, nloc = rest >> 3;
  const int m0 = ((((xcd & 3) << 3) | mloc) << 7);   // 32 m-blocks * 128
  const int n0 = ((((xcd >> 2) << 2) | nloc) << 7);  // 8 n-blocks * 128
  const u16* Bm = Bt + (size_t)i*DD*DD;
  u16* C = kraw + (size_t)i*MM*DD;
  const int t = threadIdx.x, w = t>>6, lane = t&63;
  const int q15 = lane&15, quad = lane>>4;
  const int wm = w>>1, wn = w&1;
  const int lr = lane>>3, lc = lane&7, gsw = lc ^ lr;
  const int sw = q15 & 7;
  __shared__ u16 As[128*64];
  __shared__ u16 Bs[128*64];
  f32x4 acc[4][4];
  #pragma unroll
  for(int a=0;a<4;a++)
    #pragma unroll
    for(int b2=0;b2<4;b2++) acc[a][b2] = (f32x4){0.f,0.f,0.f,0.f};

  for (int k0=0; k0<DD; k0+=64) {
    __syncthreads();
    #pragma unroll
    for (int j2=0; j2<4; j2++) {
      int r = (w*4+j2)*8 + lr;
      gl_lds16(xb + (size_t)(m0+r)*DD + k0 + gsw*8, &As[((w*4+j2)*8)*64]);
      gl_lds16(Bm + (size_t)(n0+r)*DD + k0 + gsw*8, &Bs[((w*4+j2)*8)*64]);
    }
    __syncthreads();
    #pragma unroll
    for (int kk=0; kk<2; kk++) {
      bf16x8 af[4], bfr[4];
      #pragma unroll
      for (int mt=0; mt<4; mt++)
        af[mt]  = *(bf16x8*)(&As[(wm*64+mt*16+q15)*64 + ((kk*4+quad)^sw)*8]);
      #pragma unroll
      for (int nt=0; nt<4; nt++)
        bfr[nt] = *(bf16x8*)(&Bs[(wn*64+nt*16+q15)*64 + ((kk*4+quad)^sw)*8]);
      #pragma unroll
      for (int mt=0; mt<4; mt++)
        #pragma unroll
        for (int nt=0; nt<4; nt++)
          acc[mt][nt] = __builtin_amdgcn_mfma_f32_16x16x32_bf16(af[mt], bfr[nt], acc[mt][nt], 0,0,0);
    }
  }
  #pragma unroll
  for (int mt=0; mt<4; mt++)
    #pragma unroll
    for (int nt=0; nt<4; nt++)
      #pragma unroll
      for (int r=0; r<4; r++) {
        int m = m0 + wm*64 + mt*16 + quad*4 + r;
        int n = n0 + wn*64 + nt*16 + q15;
        C[(size_t)m*DD + n] = f2bf(acc[mt][nt][r]);
      }
}

// ---------------------------------------------------------------------------
// Kernel 3: delta i=0..2 -> q' (pre-scaled) + k planes bf16, Vw[b][h][s].
__global__ void delta_qkv_kernel(const float* __restrict__ x, const u16* __restrict__ kraw,
                                 const float* __restrict__ dbw, const float* __restrict__ dbb,
                                 const float* __restrict__ wv, const float* __restrict__ cv,
                                 u16* __restrict__ qk, float* __restrict__ Vw) {
  int m = blockIdx.x, t = threadIdx.x, w = t>>6, lane = t&63;
  const float* xr = x + (size_t)m*DD;
  float4 xv = *(const float4*)(xr + t*4);
  __shared__ float4 part[3][4];
  float4 kvs[3];
  #pragma unroll
  for (int i=0;i<3;i++) {
    ushort4 ku = *(const ushort4*)(kraw + (size_t)i*MM*DD + (size_t)m*DD + t*4);
    float4 kv = make_float4(bf2f(ku.x), bf2f(ku.y), bf2f(ku.z), bf2f(ku.w));
    kvs[i] = kv;
    float4 bwv = *(const float4*)(dbw + i*DD + t*4);
    float4 wvv = *(const float4*)(wv  + i*DD + t*4);
    float4 red = make_float4(dot4f(kv,kv), dot4f(kv,xv), dot4f(xv,bwv), dot4f(xv,wvv));
    #pragma unroll
    for (int off=32; off>0; off>>=1) {
      red.x += __shfl_xor(red.x, off);
      red.y += __shfl_xor(red.y, off);
      red.z += __shfl_xor(red.z, off);
      red.w += __shfl_xor(red.w, off);
    }
    if (lane==0) part[i][w] = red;
  }
  __syncthreads();
  float cc[3];
  #pragma unroll
  for (int i=0;i<3;i++) {
    float4 r0=part[i][0], r1=part[i][1], r2=part[i][2], r3=part[i][3];
    float s0=r0.x+r1.x+r2.x+r3.x, s1=r0.y+r1.y+r2.y+r3.y;
    float s2=r0.z+r1.z+r2.z+r3.z, s3=r0.w+r1.w+r2.w+r3.w;
    float nrmE = sqrtf(s0) + 1e-8f;
    float kdh  = s1 / nrmE;
    float beta = 2.f / (1.f + __expf(-(s2 + dbb[i])));
    float vs   = s3 + cv[i];
    cc[i] = beta * (vs - kdh) / nrmE;
  }
  {
    float c = cc[0]; float4 kv = kvs[0];
    ushort4 ou;
    ou.x = f2bf((xv.x + c*kv.x)*QSCALE); ou.y = f2bf((xv.y + c*kv.y)*QSCALE);
    ou.z = f2bf((xv.z + c*kv.z)*QSCALE); ou.w = f2bf((xv.w + c*kv.w)*QSCALE);
    *(ushort4*)(qk + (size_t)m*DD + t*4) = ou;
  }
  {
    float c = cc[1]; float4 kv = kvs[1];
    ushort4 ou;
    ou.x = f2bf(xv.x + c*kv.x); ou.y = f2bf(xv.y + c*kv.y);
    ou.z = f2bf(xv.z + c*kv.z); ou.w = f2bf(xv.w + c*kv.w);
    *(ushort4*)(qk + (size_t)MM*DD + (size_t)m*DD + t*4) = ou;
  }
  {
    float c = cc[2]; float4 kv = kvs[2];
    float4 vv = make_float4(xv.x + c*kv.x, xv.y + c*kv.y, xv.z + c*kv.z, xv.w + c*kv.w);
    float4 w3 = *(const float4*)(wv + 3*DD + t*4);
    float s = dot4f(vv, w3);
    #pragma unroll
    for (int off=1; off<16; off<<=1) s += __shfl_xor(s, off);
    if ((lane & 15) == 0) {
      int head = t >> 4;
      int b = m >> 11, srow = m & (SS-1);
      Vw[((size_t)(b*HH + head))*SS + srow] = s;
    }
  }
}

// ---------------------------------------------------------------------------
// Kernel 4: split-K QK^T flash. grid (32, 16, BB*KC), block 256.
// Double-buffered K via global_load_lds DMA; ONE barrier per kt; Vw in regs.
// Plain stores into per-kc slabs (no atomics, no zero-init).
__global__ __launch_bounds__(256) void flash_mfma(const u16* __restrict__ qb,
     const u16* __restrict__ kb, const float* __restrict__ Vw,
     float* __restrict__ l_arr, float* __restrict__ pv_arr) {
  const int qt = blockIdx.x, h = blockIdx.y;
  const int b = blockIdx.z >> 2, kc = blockIdx.z & 3;
  const int t = threadIdx.x, w = t>>6, lane = t&63, q15 = lane&15, quad = lane>>4;
  const int lr = lane>>3, lc = lane&7, gsw = lc ^ lr;
  const int sw = q15 & 7;
  __shared__ u16 Qs[64*64];
  __shared__ u16 Ks[2][64*64];
  const size_t hb = (size_t)h*HD;
  const u16* kbase = kb + (size_t)(b*SS + kc*KT_PER*64)*DD + hb;
  const float* vwb = Vw + (size_t)(b*HH + h)*SS + kc*KT_PER*64;

  // stage Q + K tile 0 via DMA
  #pragma unroll
  for (int j=0; j<2; j++) {
    int r = (w*2+j)*8 + lr;
    gl_lds16(qb + (size_t)(b*SS + qt*64 + r)*DD + hb + gsw*8, &Qs[((w*2+j)*8)*64]);
    gl_lds16(kbase + (size_t)r*DD + gsw*8, &Ks[0][((w*2+j)*8)*64]);
  }
  // Vw register prefetch for kt=0 (16 lanes same addr -> broadcast)
  float4 vwreg[4];
  #pragma unroll
  for (int rt=0; rt<4; rt++) vwreg[rt] = *(const float4*)(vwb + rt*16 + quad*4);

  float l_acc = 0.f, pv_acc = 0.f;
  __syncthreads();                              // Q + K0 staged
  bf16x8 qf[2];
  #pragma unroll
  for (int kk=0; kk<2; kk++)
    qf[kk] = *(bf16x8*)(&Qs[(w*16+q15)*64 + ((kk*4+quad)^sw)*8]);

  for (int kt=0; kt<KT_PER; kt++) {
    // DMA next K tile into the other buffer (overlaps this tile's compute)
    if (kt+1 < KT_PER) {
      #pragma unroll
      for (int j=0; j<2; j++) {
        int r = (w*2+j)*8 + lr;
        gl_lds16(kbase + (size_t)((kt+1)*64 + r)*DD + gsw*8,
                 &Ks[(kt+1)&1][((w*2+j)*8)*64]);
      }
    }
    // S^T: rows = keys (rt*16+quad*4+r), cols = q (w*16+q15)
    f32x4 Sacc[4];
    #pragma unroll
    for (int rt=0; rt<4; rt++) Sacc[rt] = (f32x4){0.f,0.f,0.f,0.f};
    #pragma unroll
    for (int kk=0; kk<2; kk++) {
      #pragma unroll
      for (int rt=0; rt<4; rt++) {
        bf16x8 kf = *(bf16x8*)(&Ks[kt&1][(rt*16+q15)*64 + ((kk*4+quad)^sw)*8]);
        Sacc[rt] = __builtin_amdgcn_mfma_f32_16x16x32_bf16(kf, qf[kk], Sacc[rt], 0,0,0);
      }
    }
    float4 vwcur[4];
    #pragma unroll
    for (int rt=0; rt<4; rt++) vwcur[rt] = vwreg[rt];
    if (kt+1 < KT_PER) {
      #pragma unroll
      for (int rt=0; rt<4; rt++)
        vwreg[rt] = *(const float4*)(vwb + (kt+1)*64 + rt*16 + quad*4);
    }
    #pragma unroll
    for (int rt=0; rt<4; rt++) {
      float va[4] = {vwcur[rt].x, vwcur[rt].y, vwcur[rt].z, vwcur[rt].w};
      #pragma unroll
      for (int r=0; r<4; r++) {
        float p = EXP2F(fminf(Sacc[rt][r], 30.f));
        l_acc  += p;
        pv_acc += p * va[r];
      }
    }
    __syncthreads();   // releases Ks[kt&1] for DMA overwrite; drains next DMA
  }
  // reduce across quads (lanes sharing q column q15)
  l_acc  += __shfl_xor(l_acc, 16);  l_acc  += __shfl_xor(l_acc, 32);
  pv_acc += __shfl_xor(pv_acc, 16); pv_acc += __shfl_xor(pv_acc, 32);
  if (quad == 0) {
    int tok = b*SS + qt*64 + w*16 + q15;
    size_t idx = ((size_t)kc*MM + tok)*HH + h;
    l_arr[idx]  = l_acc;
    pv_arr[idx] = pv_acc;
  }
}

// ---------------------------------------------------------------------------
// Kernel 5: v3 = sum_h (sum_kc pv)/(sum_kc l), delta #3 + LayerNorm. grid MM.
__global__ void final_kernel(const float* __restrict__ x, const u16* __restrict__ kraw3,
                             const float* __restrict__ l_arr, const float* __restrict__ pv_arr,
                             const float* __restrict__ dbw, const float* __restrict__ dbb,
                             const float* __restrict__ cv,
                             const float* __restrict__ ln_g, const float* __restrict__ ln_b,
                             float* __restrict__ out) {
  int m = blockIdx.x, t = threadIdx.x, w = t>>6, lane = t&63;
  const float* xr = x     + (size_t)m*DD;
  const u16*   kr = kraw3 + (size_t)m*DD;
  float4 xv  = *(const float4*)(xr + t*4);
  ushort4 ku = *(const ushort4*)(kr + t*4);
  float4 kv  = make_float4(bf2f(ku.x), bf2f(ku.y), bf2f(ku.z), bf2f(ku.w));
  float4 bwv = *(const float4*)(dbw + 3*DD + t*4);
  __shared__ float4 part[4];
  __shared__ float2 part2[4];
  __shared__ float v3s;
  if (t < 16) {
    float lsum = 0.f, psum = 0.f;
    #pragma unroll
    for (int kc=0; kc<KC; kc++) {
      size_t idx = ((size_t)kc*MM + m)*HH + t;
      lsum += l_arr[idx];
      psum += pv_arr[idx];
    }
    float val = psum / lsum;
    #pragma unroll
    for (int off=1; off<16; off<<=1) val += __shfl_xor(val, off);
    if (t==0) v3s = val;
  }
  float4 red = make_float4(dot4f(kv,kv), dot4f(kv,xv), dot4f(xv,bwv), 0.f);
  #pragma unroll
  for (int off=32; off>0; off>>=1) {
    red.x += __shfl_xor(red.x, off);
    red.y += __shfl_xor(red.y, off);
    red.z += __shfl_xor(red.z, off);
  }
  if (lane==0) part[w] = red;
  __syncthreads();
  float4 r0=part[0], r1=part[1], r2=part[2], r3=part[3];
  float s0=r0.x+r1.x+r2.x+r3.x, s1=r0.y+r1.y+r2.y+r3.y, s2=r0.z+r1.z+r2.z+r3.z;
  float nrmE = sqrtf(s0) + 1e-8f;
  float kdh  = s1 / nrmE;
  float beta = 2.f / (1.f + __expf(-(s2 + dbb[3])));
  float v3   = v3s + cv[3];
  float c = beta * (v3 - kdh) / nrmE;
  float y0 = xv.x + c*kv.x, y1 = xv.y + c*kv.y, y2 = xv.z + c*kv.z, y3 = xv.w + c*kv.w;
  float2 rr = make_float2(y0+y1+y2+y3, y0*y0+y1*y1+y2*y2+y3*y3);
  #pragma unroll
  for (int off=32; off>0; off>>=1) {
    rr.x += __shfl_xor(rr.x, off);
    rr.y += __shfl_xor(rr.y, off);
  }
  if (lane==0) part2[w] = rr;
  __syncthreads();
  float ssum = part2[0].x+part2[1].x+part2[2].x+part2[3].x;
  float ssq  = part2[0].y+part2[1].y+part2[2].y+part2[3].y;
  float mu   = ssum * (1.f/DD);
  float var  = ssq * (1.f/DD) - mu*mu;
  float rstd = rsqrtf(var + 1e-5f);
  float4 g  = *(const float4*)(ln_g + t*4);
  float4 bb = *(const float4*)(ln_b + t*4);
  float4 ov;
  ov.x = (y0-mu)*rstd*g.x + bb.x;
  ov.y = (y1-mu)*rstd*g.y + bb.y;
  ov.z = (y2-mu)*rstd*g.z + bb.z;
  ov.w = (y3-mu)*rstd*g.w + bb.w;
  *(float4*)(out + (size_t)m*DD + t*4) = ov;
}

// ---------------------------------------------------------------------------
extern "C" void kernel_launch(void* const* d_in, const int* in_sizes, int n_in,
                              void* d_out, int out_size, void* d_ws, size_t ws_size,
                              hipStream_t stream) {
  const float* x    = (const float*)d_in[0];
  const float* Wq_  = (const float*)d_in[1];
  const float* bq_  = (const float*)d_in[2];
  const float* Wk_  = (const float*)d_in[3];
  const float* bk_  = (const float*)d_in[4];
  const float* Wv_  = (const float*)d_in[5];
  const float* bv_  = (const float*)d_in[6];
  const float* Wo_  = (const float*)d_in[7];
  const float* bo_  = (const float*)d_in[8];
  const float* dWk  = (const float*)d_in[9];
  const float* dbw  = (const float*)d_in[10];
  const float* dbb  = (const float*)d_in[11];
  const float* dWv  = (const float*)d_in[12];
  const float* dbv  = (const float*)d_in[13];
  const float* ln_g = (const float*)d_in[14];
  const float* ln_b = (const float*)d_in[15];
  float* out = (float*)d_out;
  char* WS = (char*)d_ws;

  // workspace layout (bytes):
  float* wv     = (float*)WS;                                 // 16 KB
  float* cv     = (float*)(WS + 16384);                       // 256 B
  u16*   kraw   = (u16*)  (WS + 16640);                       // 4*MM*DD bf16 = 33.5 MB
  u16*   qk     = (u16*)  (WS + 16640 + (size_t)4*MM*DD*2);   // 2*MM*DD bf16 = 16.8 MB
  u16*   dWkT   = (u16*)  (WS + 16640 + (size_t)6*MM*DD*2);   // 8.4 MB
  u16*   xb     = (u16*)  (WS + 16640 + (size_t)6*MM*DD*2 + (size_t)4*DD*DD*2); // 8.4 MB
  char*  tail   = WS + 16640 + (size_t)6*MM*DD*2 + (size_t)8*DD*DD*2;
  float* Vw     = (float*)tail;                               // BB*HH*SS f32 = 256 KB
  float* l_arr  = (float*)(tail + (size_t)BB*HH*SS*4);        // KC*MM*HH f32 = 1 MB
  float* pv_arr = (float*)(tail + (size_t)BB*HH*SS*4 + (size_t)KC*MM*HH*4); // 1 MB

  prep_kernel<<<NB_PREP, 256, 0, stream>>>(
      x, xb, dWk, dWkT, Wq_,bq_,Wk_,bk_,Wv_,bv_,Wo_,bo_, dWv, dbv, wv, cv);
  gemm_dwk_mfma<<<1024, 256, 0, stream>>>(xb, dWkT, kraw);
  delta_qkv_kernel<<<MM, 256, 0, stream>>>(x, kraw, dbw, dbb, wv, cv, qk, Vw);
  flash_mfma<<<dim3(SS/64, HH, BB*KC), 256, 0, stream>>>(
      qk, qk + (size_t)MM*DD, Vw, l_arr, pv_arr);
  final_kernel<<<MM, 256, 0, stream>>>(x, kraw + 3*(size_t)MM*DD, l_arr, pv_arr,
                                       dbw, dbb, cv, ln_g, ln_b, out);
}